// Round 12
// baseline (716.709 us; speedup 1.0000x reference)
//
#include <hip/hip_runtime.h>

#define NN 50000
#define NE 1600000
#define NG 16
#define HID 128
#define NEXP 4
#define LOGN_SCALE 9.210340371976184f

#define NBUK 256     // dst buckets
#define NPB  196     // nodes per bucket
#define NBLK 128     // hist/scatter blocks
#define EPB  ((NE + NBLK - 1)/NBLK)   // 12500 edges per block
#define MAXB 16384   // k_build LDS capacity per bucket (mean 6272)

typedef unsigned short u16;
typedef unsigned int u32;
typedef unsigned char u8;
typedef __attribute__((ext_vector_type(8))) short short8b;   // 8 bf16 = 4 VGPR
typedef __attribute__((ext_vector_type(4))) float f32x4;
typedef __attribute__((ext_vector_type(2))) float f32x2;

static __device__ __forceinline__ u16 f2bf(float f){
  union { float f; u32 i; } c; c.f = f;
  return (u16)((c.i + 0x7fffu + ((c.i>>16)&1u)) >> 16);
}
static __device__ __forceinline__ u8 f2fp8(float v){
  return (u8)(__builtin_amdgcn_cvt_pk_fp8_f32(v, v, 0, false) & 0xffu);
}
// 8 packed fp8 -> 8 bf16 (table units)
static __device__ __forceinline__ short8b fp8x8_to_bf16(uint2 v){
  f32x2 a = __builtin_amdgcn_cvt_pk_f32_fp8(v.x, false);
  f32x2 b = __builtin_amdgcn_cvt_pk_f32_fp8(v.x, true);
  f32x2 c = __builtin_amdgcn_cvt_pk_f32_fp8(v.y, false);
  f32x2 d = __builtin_amdgcn_cvt_pk_f32_fp8(v.y, true);
  short8b t;
  t[0]=(short)f2bf(a.x); t[1]=(short)f2bf(a.y);
  t[2]=(short)f2bf(b.x); t[3]=(short)f2bf(b.y);
  t[4]=(short)f2bf(c.x); t[5]=(short)f2bf(c.y);
  t[6]=(short)f2bf(d.x); t[7]=(short)f2bf(d.y);
  return t;
}

// ---- graph boundaries via binary search (batch is sorted) ----
__global__ void k_bounds(const int* __restrict__ batch, int* __restrict__ gstart){
  int g = threadIdx.x;
  if(g > NG) return;
  int lo = 0, hi = NN;
  while(lo < hi){ int mid = (lo+hi)>>1; if(batch[mid] < g) lo = mid+1; else hi = mid; }
  gstart[g] = lo;
}

// ---- per-node expert probs ----
__global__ void k_probs(const int* __restrict__ batch, const int* __restrict__ gstart,
                        const float* __restrict__ centers, float* __restrict__ probs){
  int n = blockIdx.x*blockDim.x + threadIdx.x;
  if(n >= NN) return;
  int b = batch[n];
  float c = (float)(gstart[b+1] - gstart[b]);
  float logn = logf(fmaxf(c, 1.f)) * (1.f/LOGN_SCALE);
  float s[NEXP]; float m = -1e30f;
  #pragma unroll
  for(int e=0;e<NEXP;e++){ float d = logn - centers[e]; s[e] = -d*d; m = fmaxf(m, s[e]); }
  float sum = 0.f;
  #pragma unroll
  for(int e=0;e<NEXP;e++){ s[e] = expf(s[e]-m); sum += s[e]; }
  float inv = 1.f/sum;
  #pragma unroll
  for(int e=0;e<NEXP;e++) probs[n*NEXP+e] = s[e]*inv;
}

// ---- encoder: h08 = fp8(relu(x @ Wenc + benc) * esc) ----
__global__ void k_enc(const float* __restrict__ x, const float* __restrict__ Wenc,
                      const float* __restrict__ benc, u8* __restrict__ h08, float esc){
  int t = blockIdx.x*blockDim.x + threadIdx.x;
  if(t >= NN*HID) return;
  int n = t >> 7, j = t & 127;
  float acc = benc[j];
  #pragma unroll
  for(int k=0;k<6;k++) acc += x[n*6+k]*Wenc[k*HID+j];
  h08[t] = f2fp8(fmaxf(acc, 0.f)*esc);
}

// ---- weights -> bf16, transposed+concatenated: WbfT[(e*3+l)][col j][k 0..255] ----
__global__ void k_wcvtT(const float* __restrict__ Wself, const float* __restrict__ Wnbr,
                        u16* __restrict__ WbfT){
  int t = blockIdx.x*blockDim.x + threadIdx.x;
  if(t >= 12*HID*256) return;
  int el = t / (HID*256);
  int r  = t % (HID*256);
  int j  = r >> 8;
  int k  = r & 255;
  float v = (k < HID) ? Wself[(size_t)el*HID*HID + (size_t)k*HID + j]
                      : Wnbr [(size_t)el*HID*HID + (size_t)(k-HID)*HID + j];
  WbfT[t] = f2bf(v);
}

// ==== bucketed CSR build ====
__global__ __launch_bounds__(256) void k_hist(const int* __restrict__ dst,
                                              int* __restrict__ hist){
  __shared__ int h[NBUK];
  for(int i=threadIdx.x; i<NBUK; i+=256) h[i] = 0;
  __syncthreads();
  int e0 = blockIdx.x*EPB, e1 = min(NE, e0 + EPB);
  for(int e = e0 + (int)threadIdx.x; e < e1; e += 256)
    atomicAdd(&h[dst[e]/NPB], 1);
  __syncthreads();
  for(int i=threadIdx.x; i<NBUK; i+=256) hist[blockIdx.x*NBUK + i] = h[i];
}

__global__ __launch_bounds__(1024) void k_hscan(const int* __restrict__ hist,
                                                int* __restrict__ hoff,
                                                int* __restrict__ bbase){
  __shared__ int sd[NBLK*NBUK];
  __shared__ int ps[1024];
  int t = threadIdx.x;
  for(int i=t; i<NBLK*NBUK; i+=1024){
    int bucket = i >> 7;
    int blk = i & (NBLK-1);
    sd[i] = hist[blk*NBUK + bucket];
  }
  __syncthreads();
  int base = t*32, sum = 0;
  #pragma unroll
  for(int i=0;i<32;i++){ int v = sd[base+i]; sd[base+i] = sum; sum += v; }
  ps[t] = sum;
  __syncthreads();
  for(int d=1; d<1024; d<<=1){
    int v = (t>=d) ? ps[t-d] : 0;
    __syncthreads();
    ps[t] += v;
    __syncthreads();
  }
  int add = (t>0) ? ps[t-1] : 0;
  for(int i=base; i<base+32; i++){
    int bucket = i >> 7, blk = i & (NBLK-1);
    int v = sd[i] + add;
    hoff[blk*NBUK + bucket] = v;
    if(blk == 0) bbase[bucket] = v;
  }
  if(t == 1023) bbase[NBUK] = NE;
}

__global__ __launch_bounds__(256) void k_scatter(const int* __restrict__ src,
                                                 const int* __restrict__ dst,
                                                 const int* __restrict__ hoff,
                                                 u32* __restrict__ packed){
  __shared__ u32 ent[EPB];
  __shared__ u32 outp[EPB];
  __shared__ u32 cnt[NBUK], exc[NBUK], cur[NBUK], gb[NBUK];
  int t = threadIdx.x;
  int e0 = blockIdx.x*EPB;
  int len = min(EPB, NE - e0);
  cnt[t] = 0;
  __syncthreads();
  for(int i=t; i<len; i+=256){
    int d = dst[e0+i];
    u32 b = (u32)(d/NPB);
    ent[i] = (u32)src[e0+i] | ((u32)(d - (int)b*NPB) << 16) | (b << 24);
    atomicAdd(&cnt[b], 1u);
  }
  __syncthreads();
  u32 c = cnt[t];
  exc[t] = c;
  __syncthreads();
  for(int d=1; d<256; d<<=1){
    u32 v = (t>=(u32)d) ? exc[t-d] : 0u;
    __syncthreads();
    exc[t] += v;
    __syncthreads();
  }
  u32 excl = exc[t] - c;
  cur[t] = excl;
  gb[t] = (u32)hoff[blockIdx.x*NBUK + t];
  __syncthreads();
  exc[t] = excl;
  __syncthreads();
  for(int i=t; i<len; i+=256){
    u32 v = ent[i];
    u32 p = atomicAdd(&cur[v>>24], 1u);
    outp[p] = v;
  }
  __syncthreads();
  for(int i=t; i<len; i+=256){
    u32 v = outp[i];
    u32 b = v >> 24;
    packed[gb[b] + ((u32)i - exc[b])] = v & 0x00ffffffu;
  }
}

__global__ __launch_bounds__(256) void k_build(const u32* __restrict__ packed,
                                               const int* __restrict__ bbase,
                                               int* __restrict__ offs,
                                               u16* __restrict__ srcs16){
  __shared__ u32 ent[MAXB];
  __shared__ u16 outb[MAXB];
  __shared__ u32 cnt[256], exc[256], cur[256];
  int b = blockIdx.x, t = threadIdx.x;
  int e0 = bbase[b], e1 = bbase[b+1];
  int len = e1 - e0, cap = min(len, MAXB);
  for(int i=t; i<cap; i+=256) ent[i] = packed[e0+i];
  cnt[t] = 0;
  __syncthreads();
  for(int i=t; i<len; i+=256){
    u32 v = (i < MAXB) ? ent[i] : packed[e0+i];
    atomicAdd(&cnt[(v>>16)&0xffu], 1u);
  }
  __syncthreads();
  u32 c = cnt[t];
  exc[t] = c;
  __syncthreads();
  for(int d=1; d<256; d<<=1){
    u32 v = (t>=(u32)d) ? exc[t-d] : 0u;
    __syncthreads();
    exc[t] += v;
    __syncthreads();
  }
  u32 excl = exc[t] - c;
  int node = b*NPB + t;
  if(t < NPB && node < NN) offs[node] = e0 + (int)excl;
  cur[t] = excl;
  if(b == NBUK-1 && t == 0) offs[NN] = NE;
  __syncthreads();
  for(int i=t; i<len; i+=256){
    u32 v = (i < MAXB) ? ent[i] : packed[e0+i];
    u32 p = atomicAdd(&cur[(v>>16)&0xffu], 1u);
    u16 sv = (u16)(v & 0xffffu);
    if(p < (u32)MAXB) outb[p] = sv;
    else srcs16[e0+p] = sv;
  }
  __syncthreads();
  for(int i=t; i<cap; i+=256) srcs16[e0+i] = outb[i];
}

// ---- aggregation over fp8 table: ONE WAVE PER NODE, no LDS, no barrier ----
// Output bf16 in TABLE (scaled) units: agg_scaled = sum of fp8 values.
template<int BPL>
__global__ __launch_bounds__(256) void k_agg8(const u8* __restrict__ hin,
                                              const int* __restrict__ offs,
                                              const u16* __restrict__ srcs,
                                              u16* __restrict__ hout){
  const int W = BPL*64;
  int node = blockIdx.x*4 + (threadIdx.x>>6);
  if(node >= NN) return;
  int lane = threadIdx.x & 63;
  const u8* hbase = hin + lane*BPL;
  float acc[BPL];
  #pragma unroll
  for(int i=0;i<BPL;i++) acc[i] = 0.f;
  int beg = offs[node], end = offs[node+1];
  for(int eb=beg; eb<end; eb+=64){
    int idx = eb + lane;
    int s = (idx < end) ? (int)srcs[idx] : 0;
    int cnt = min(64, end-eb);
    int j = 0;
    if(BPL == 8){
      for(; j+8<=cnt; j+=8){
        uint2 v[8];
        #pragma unroll
        for(int u=0;u<8;u++){
          int sj = __shfl(s, j+u, 64);
          v[u] = *(const uint2*)(hbase + (size_t)sj*W);
        }
        #pragma unroll
        for(int u=0;u<8;u++){
          f32x2 f0 = __builtin_amdgcn_cvt_pk_f32_fp8(v[u].x, false);
          f32x2 f1 = __builtin_amdgcn_cvt_pk_f32_fp8(v[u].x, true);
          f32x2 f2 = __builtin_amdgcn_cvt_pk_f32_fp8(v[u].y, false);
          f32x2 f3 = __builtin_amdgcn_cvt_pk_f32_fp8(v[u].y, true);
          acc[0]+=f0.x; acc[1]+=f0.y; acc[2]+=f1.x; acc[3]+=f1.y;
          acc[4]+=f2.x; acc[5]+=f2.y; acc[6]+=f3.x; acc[7]+=f3.y;
        }
      }
      for(; j<cnt; j++){
        int sj = __shfl(s, j, 64);
        uint2 v = *(const uint2*)(hbase + (size_t)sj*W);
        f32x2 f0 = __builtin_amdgcn_cvt_pk_f32_fp8(v.x, false);
        f32x2 f1 = __builtin_amdgcn_cvt_pk_f32_fp8(v.x, true);
        f32x2 f2 = __builtin_amdgcn_cvt_pk_f32_fp8(v.y, false);
        f32x2 f3 = __builtin_amdgcn_cvt_pk_f32_fp8(v.y, true);
        acc[0]+=f0.x; acc[1]+=f0.y; acc[2]+=f1.x; acc[3]+=f1.y;
        acc[4]+=f2.x; acc[5]+=f2.y; acc[6]+=f3.x; acc[7]+=f3.y;
      }
    } else {
      for(; j+8<=cnt; j+=8){
        u32 v[8];
        #pragma unroll
        for(int u=0;u<8;u++){
          int sj = __shfl(s, j+u, 64);
          v[u] = *(const u16*)(hbase + (size_t)sj*W);
        }
        #pragma unroll
        for(int u=0;u<8;u++){
          f32x2 f0 = __builtin_amdgcn_cvt_pk_f32_fp8(v[u], false);
          acc[0]+=f0.x; acc[1]+=f0.y;
        }
      }
      for(; j<cnt; j++){
        int sj = __shfl(s, j, 64);
        u32 v = *(const u16*)(hbase + (size_t)sj*W);
        f32x2 f0 = __builtin_amdgcn_cvt_pk_f32_fp8(v, false);
        acc[0]+=f0.x; acc[1]+=f0.y;
      }
    }
  }
  u16* o = hout + (size_t)node*W + lane*BPL;
  #pragma unroll
  for(int i=0;i<BPL;i++) o[i] = f2bf(acc[i]);
}

// ==== GEMM: [self(fp8 table) | agg(bf16 scaled)] @ [Ws;Wn] + b, swapped-operand MFMA ====
// 256 thr / 4 waves, 16 nodes per block. Non-LAST: wave = expert, fp8 table out.
// LAST: wave = 32-col slice, probs-combined fp32 out.
template<int TW, bool RELU, bool LAST>
__global__ __launch_bounds__(256) void k_gemm8(
    const u8* __restrict__ tin, const u16* __restrict__ aggb,
    const u16* __restrict__ WbfT, const float* __restrict__ bconv, int layer,
    const float* __restrict__ probs,
    u8* __restrict__ tout, float* __restrict__ outp,
    float bias_fold, float store_fold)
{
  int wave = threadIdx.x>>6, lane = threadIdx.x&63;
  int l16 = lane&15, lq = lane>>4;
  int n0 = blockIdx.x*16;
  int na = n0 + l16; if(na > NN-1) na = NN-1;
  const u8*  srow = tin  + (size_t)na*TW;
  const u16* arow = aggb + (size_t)na*TW;

  if(!LAST){
    int e = wave;
    const u16* WT = WbfT + (size_t)((e*3+layer)*HID)*256;
    const int eoff = (TW==512) ? e*128 : 0;
    short8b Af[8];
    #pragma unroll
    for(int ks=0; ks<4; ks++)
      Af[ks] = fp8x8_to_bf16(*(const uint2*)(srow + eoff + ks*32 + lq*8));
    #pragma unroll
    for(int ks=4; ks<8; ks++)
      Af[ks] = *(const short8b*)(arow + eoff + (ks-4)*32 + lq*8);
    const float* bias = bconv + (e*3+layer)*HID;
    #pragma unroll 1
    for(int ct=0; ct<8; ct++){
      f32x4 binit = *(const f32x4*)(bias + ct*16 + lq*4);
      f32x4 acc;
      #pragma unroll
      for(int r=0;r<4;r++) acc[r] = binit[r]*bias_fold;
      const u16* wp = WT + (size_t)(ct*16 + l16)*256 + lq*8;
      #pragma unroll
      for(int ks=0; ks<8; ks++){
        short8b Bf = *(const short8b*)(wp + ks*32);
        acc = __builtin_amdgcn_mfma_f32_16x16x32_bf16(Bf, Af[ks], acc, 0,0,0);
      }
      int n = n0 + l16;
      if(n < NN){
        float v0,v1,v2,v3;
        if(RELU){
          v0=fmaxf(acc[0],0.f)*store_fold; v1=fmaxf(acc[1],0.f)*store_fold;
          v2=fmaxf(acc[2],0.f)*store_fold; v3=fmaxf(acc[3],0.f)*store_fold;
        } else {
          v0=acc[0]*store_fold; v1=acc[1]*store_fold;
          v2=acc[2]*store_fold; v3=acc[3]*store_fold;
        }
        u32 wv = __builtin_amdgcn_cvt_pk_fp8_f32(v0, v1, 0, false);
        wv = __builtin_amdgcn_cvt_pk_fp8_f32(v2, v3, wv, true);
        *(u32*)(tout + (size_t)n*512 + e*128 + ct*16 + lq*4) = wv;
      }
    }
  } else {
    int cs = wave*32;
    f32x4 tot[2];
    #pragma unroll
    for(int ct=0;ct<2;ct++){
      #pragma unroll
      for(int r=0;r<4;r++) tot[ct][r] = 0.f;
    }
    float pv[4];
    #pragma unroll
    for(int e=0;e<4;e++) pv[e] = probs[na*NEXP + e];
    #pragma unroll 1
    for(int e=0;e<4;e++){
      const u16* WT = WbfT + (size_t)((e*3+layer)*HID)*256;
      const int eoff = e*128;
      short8b Af[8];
      #pragma unroll
      for(int ks=0; ks<4; ks++)
        Af[ks] = fp8x8_to_bf16(*(const uint2*)(srow + eoff + ks*32 + lq*8));
      #pragma unroll
      for(int ks=4; ks<8; ks++)
        Af[ks] = *(const short8b*)(arow + eoff + (ks-4)*32 + lq*8);
      const float* bias = bconv + (e*3+layer)*HID;
      #pragma unroll
      for(int ct=0; ct<2; ct++){
        int cb = cs + ct*16;
        f32x4 binit = *(const f32x4*)(bias + cb + lq*4);
        f32x4 acc;
        #pragma unroll
        for(int r=0;r<4;r++) acc[r] = binit[r]*bias_fold;
        const u16* wp = WT + (size_t)(cb + l16)*256 + lq*8;
        #pragma unroll
        for(int ks=0; ks<8; ks++){
          short8b Bf = *(const short8b*)(wp + ks*32);
          acc = __builtin_amdgcn_mfma_f32_16x16x32_bf16(Bf, Af[ks], acc, 0,0,0);
        }
        float s0 = pv[e]*store_fold;
        #pragma unroll
        for(int r=0;r<4;r++) tot[ct][r] += s0*acc[r];
      }
    }
    int n = n0 + l16;
    if(n < NN){
      #pragma unroll
      for(int ct=0; ct<2; ct++)
        *(f32x4*)(outp + (size_t)n*HID + cs + ct*16 + lq*4) = tot[ct];
    }
  }
}

extern "C" void kernel_launch(void* const* d_in, const int* in_sizes, int n_in,
                              void* d_out, int out_size, void* d_ws, size_t ws_size,
                              hipStream_t stream){
  const float* x      = (const float*)d_in[0];
  const int*   eidx   = (const int*)d_in[1];
  const int*   batch  = (const int*)d_in[2];
  const float* Wenc   = (const float*)d_in[3];
  const float* benc   = (const float*)d_in[4];
  const float* Wself  = (const float*)d_in[5];
  const float* Wnbr   = (const float*)d_in[6];
  const float* bconv  = (const float*)d_in[7];
  const float* centers= (const float*)d_in[8];
  float* out = (float*)d_out;
  const int* src = eidx;
  const int* dst = eidx + NE;

  char* w = (char*)d_ws;
  size_t off = 0;
  auto alloc = [&](size_t b)->char*{ char* p = w + off; off = (off + b + 255) & ~(size_t)255; return p; };

  u8*  h08   = (u8*)alloc((size_t)NN*HID);            // 6.4 MB
  u8*  hA8   = (u8*)alloc((size_t)NN*NEXP*HID);       // 25.6 MB
  u8*  hB8   = (u8*)alloc((size_t)NN*NEXP*HID);       // 25.6 MB
  u16* aggb  = (u16*)alloc((size_t)NN*NEXP*HID*2);    // 51.2 MB (bf16, scaled units)
  u16* WbfT  = (u16*)alloc((size_t)12*HID*256*2);     // 1.57 MB
  float* probs = (float*)alloc((size_t)NN*NEXP*4);
  int* gstart = (int*)alloc(256);
  int* offs  = (int*)alloc((size_t)(NN+1)*4);
  u32* packed= (u32*)alloc((size_t)NE*4);
  u16* srcs16= (u16*)alloc((size_t)NE*2);
  int* hist  = (int*)alloc((size_t)NBLK*NBUK*4);
  int* hoff  = (int*)alloc((size_t)NBLK*NBUK*4);
  int* bbase = (int*)alloc((size_t)(NBUK+1)*4);
  if(off > ws_size) return;

  k_bounds<<<1, 32, 0, stream>>>(batch, gstart);
  k_probs<<<(NN+255)/256, 256, 0, stream>>>(batch, gstart, centers, probs);
  k_enc<<<(NN*HID+255)/256, 256, 0, stream>>>(x, Wenc, benc, h08, 0.5f);
  k_wcvtT<<<(12*HID*256+255)/256, 256, 0, stream>>>(Wself, Wnbr, WbfT);

  k_hist<<<NBLK, 256, 0, stream>>>(dst, hist);
  k_hscan<<<1, 1024, 0, stream>>>(hist, hoff, bbase);
  k_scatter<<<NBLK, 256, 0, stream>>>(src, dst, hoff, packed);
  k_build<<<NBUK, 256, 0, stream>>>(packed, bbase, offs, srcs16);

  int agrid = (NN+3)/4;        // 12500: one wave per node
  int ggrid = (NN+15)/16;      // 3125: 16 nodes per block
  // scales: esc0=0.5, escA=1/16, escB=1/32 ; agg stays in table (scaled) units
  k_agg8<2><<<agrid, 256, 0, stream>>>(h08, offs, srcs16, aggb);
  k_gemm8<128,true,false><<<ggrid, 256, 0, stream>>>(
      h08, aggb, WbfT, bconv, 0, nullptr, hA8, nullptr, 0.5f, 0.125f);
  k_agg8<8><<<agrid, 256, 0, stream>>>(hA8, offs, srcs16, aggb);
  k_gemm8<512,true,false><<<ggrid, 256, 0, stream>>>(
      hA8, aggb, WbfT, bconv, 1, nullptr, hB8, nullptr, 0.0625f, 0.5f);
  k_agg8<8><<<agrid, 256, 0, stream>>>(hB8, offs, srcs16, aggb);
  k_gemm8<512,false,true><<<ggrid, 256, 0, stream>>>(
      hB8, aggb, WbfT, bconv, 2, probs, nullptr, out, 0.03125f, 32.0f);
}

// Round 13
// 579.102 us; speedup vs baseline: 1.2376x; 1.2376x over previous
//
#include <hip/hip_runtime.h>

#define NN 50000
#define NE 1600000
#define NG 16
#define HID 128
#define NEXP 4
#define LOGN_SCALE 9.210340371976184f

#define NBUK 256
#define NPB  196
#define NBLK 128
#define EPB  ((NE + NBLK - 1)/NBLK)
#define MAXB 16384
#define RPB  256   // nodes per gemm block

typedef unsigned short u16;
typedef unsigned int u32;
typedef unsigned char u8;
typedef __attribute__((ext_vector_type(8))) short short8b;
typedef __attribute__((ext_vector_type(4))) float f32x4;
typedef __attribute__((ext_vector_type(2))) float f32x2;
typedef __attribute__((ext_vector_type(4))) unsigned short ushort4v;

static __device__ __forceinline__ float bf2f(u16 u){
  union { u32 i; float f; } c; c.i = ((u32)u)<<16; return c.f;
}
static __device__ __forceinline__ u16 f2bf(float f){
  union { float f; u32 i; } c; c.f = f;
  return (u16)((c.i + 0x7fffu + ((c.i>>16)&1u)) >> 16);
}
static __device__ __forceinline__ u8 f2fp8(float v){
  return (u8)(__builtin_amdgcn_cvt_pk_fp8_f32(v, v, 0, false) & 0xffu);
}
static __device__ __forceinline__ short8b fp8x8_to_bf16(uint2 v){
  f32x2 a = __builtin_amdgcn_cvt_pk_f32_fp8(v.x, false);
  f32x2 b = __builtin_amdgcn_cvt_pk_f32_fp8(v.x, true);
  f32x2 c = __builtin_amdgcn_cvt_pk_f32_fp8(v.y, false);
  f32x2 d = __builtin_amdgcn_cvt_pk_f32_fp8(v.y, true);
  short8b t;
  t[0]=(short)f2bf(a.x); t[1]=(short)f2bf(a.y);
  t[2]=(short)f2bf(b.x); t[3]=(short)f2bf(b.y);
  t[4]=(short)f2bf(c.x); t[5]=(short)f2bf(c.y);
  t[6]=(short)f2bf(d.x); t[7]=(short)f2bf(d.y);
  return t;
}

// ---- graph boundaries ----
__global__ void k_bounds(const int* __restrict__ batch, int* __restrict__ gstart){
  int g = threadIdx.x;
  if(g > NG) return;
  int lo = 0, hi = NN;
  while(lo < hi){ int mid = (lo+hi)>>1; if(batch[mid] < g) lo = mid+1; else hi = mid; }
  gstart[g] = lo;
}

// ---- per-node expert probs ----
__global__ void k_probs(const int* __restrict__ batch, const int* __restrict__ gstart,
                        const float* __restrict__ centers, float* __restrict__ probs){
  int n = blockIdx.x*blockDim.x + threadIdx.x;
  if(n >= NN) return;
  int b = batch[n];
  float c = (float)(gstart[b+1] - gstart[b]);
  float logn = logf(fmaxf(c, 1.f)) * (1.f/LOGN_SCALE);
  float s[NEXP]; float m = -1e30f;
  #pragma unroll
  for(int e=0;e<NEXP;e++){ float d = logn - centers[e]; s[e] = -d*d; m = fmaxf(m, s[e]); }
  float sum = 0.f;
  #pragma unroll
  for(int e=0;e<NEXP;e++){ s[e] = expf(s[e]-m); sum += s[e]; }
  float inv = 1.f/sum;
  #pragma unroll
  for(int e=0;e<NEXP;e++) probs[n*NEXP+e] = s[e]*inv;
}

// ---- encoder ----
__global__ void k_enc(const float* __restrict__ x, const float* __restrict__ Wenc,
                      const float* __restrict__ benc, u8* __restrict__ h08, float esc){
  int t = blockIdx.x*blockDim.x + threadIdx.x;
  if(t >= NN*HID) return;
  int n = t >> 7, j = t & 127;
  float acc = benc[j];
  #pragma unroll
  for(int k=0;k<6;k++) acc += x[n*6+k]*Wenc[k*HID+j];
  h08[t] = f2fp8(fmaxf(acc, 0.f)*esc);
}

// ---- weights -> bf16 transposed ----
__global__ void k_wcvtT(const float* __restrict__ Wself, const float* __restrict__ Wnbr,
                        u16* __restrict__ WbfT){
  int t = blockIdx.x*blockDim.x + threadIdx.x;
  if(t >= 12*HID*256) return;
  int el = t / (HID*256);
  int r  = t % (HID*256);
  int j  = r >> 8;
  int k  = r & 255;
  float v = (k < HID) ? Wself[(size_t)el*HID*HID + (size_t)k*HID + j]
                      : Wnbr [(size_t)el*HID*HID + (size_t)(k-HID)*HID + j];
  WbfT[t] = f2bf(v);
}

// ==== bucketed CSR build ====
__global__ __launch_bounds__(256) void k_hist(const int* __restrict__ dst,
                                              int* __restrict__ hist){
  __shared__ int h[NBUK];
  for(int i=threadIdx.x; i<NBUK; i+=256) h[i] = 0;
  __syncthreads();
  int e0 = blockIdx.x*EPB, e1 = min(NE, e0 + EPB);
  for(int e = e0 + (int)threadIdx.x; e < e1; e += 256)
    atomicAdd(&h[dst[e]/NPB], 1);
  __syncthreads();
  for(int i=threadIdx.x; i<NBUK; i+=256) hist[blockIdx.x*NBUK + i] = h[i];
}

__global__ __launch_bounds__(1024) void k_hscan(const int* __restrict__ hist,
                                                int* __restrict__ hoff,
                                                int* __restrict__ bbase){
  __shared__ int sd[NBLK*NBUK];
  __shared__ int ps[1024];
  int t = threadIdx.x;
  for(int i=t; i<NBLK*NBUK; i+=1024){
    int bucket = i >> 7;
    int blk = i & (NBLK-1);
    sd[i] = hist[blk*NBUK + bucket];
  }
  __syncthreads();
  int base = t*32, sum = 0;
  #pragma unroll
  for(int i=0;i<32;i++){ int v = sd[base+i]; sd[base+i] = sum; sum += v; }
  ps[t] = sum;
  __syncthreads();
  for(int d=1; d<1024; d<<=1){
    int v = (t>=d) ? ps[t-d] : 0;
    __syncthreads();
    ps[t] += v;
    __syncthreads();
  }
  int add = (t>0) ? ps[t-1] : 0;
  for(int i=base; i<base+32; i++){
    int bucket = i >> 7, blk = i & (NBLK-1);
    int v = sd[i] + add;
    hoff[blk*NBUK + bucket] = v;
    if(blk == 0) bbase[bucket] = v;
  }
  if(t == 1023) bbase[NBUK] = NE;
}

__global__ __launch_bounds__(256) void k_scatter(const int* __restrict__ src,
                                                 const int* __restrict__ dst,
                                                 const int* __restrict__ hoff,
                                                 u32* __restrict__ packed){
  __shared__ u32 ent[EPB];
  __shared__ u32 outp[EPB];
  __shared__ u32 cnt[NBUK], exc[NBUK], cur[NBUK], gb[NBUK];
  int t = threadIdx.x;
  int e0 = blockIdx.x*EPB;
  int len = min(EPB, NE - e0);
  cnt[t] = 0;
  __syncthreads();
  for(int i=t; i<len; i+=256){
    int d = dst[e0+i];
    u32 b = (u32)(d/NPB);
    ent[i] = (u32)src[e0+i] | ((u32)(d - (int)b*NPB) << 16) | (b << 24);
    atomicAdd(&cnt[b], 1u);
  }
  __syncthreads();
  u32 c = cnt[t];
  exc[t] = c;
  __syncthreads();
  for(int d=1; d<256; d<<=1){
    u32 v = (t>=(u32)d) ? exc[t-d] : 0u;
    __syncthreads();
    exc[t] += v;
    __syncthreads();
  }
  u32 excl = exc[t] - c;
  cur[t] = excl;
  gb[t] = (u32)hoff[blockIdx.x*NBUK + t];
  __syncthreads();
  exc[t] = excl;
  __syncthreads();
  for(int i=t; i<len; i+=256){
    u32 v = ent[i];
    u32 p = atomicAdd(&cur[v>>24], 1u);
    outp[p] = v;
  }
  __syncthreads();
  for(int i=t; i<len; i+=256){
    u32 v = outp[i];
    u32 b = v >> 24;
    packed[gb[b] + ((u32)i - exc[b])] = v & 0x00ffffffu;
  }
}

__global__ __launch_bounds__(256) void k_build(const u32* __restrict__ packed,
                                               const int* __restrict__ bbase,
                                               int* __restrict__ offs,
                                               u16* __restrict__ srcs16){
  __shared__ u32 ent[MAXB];
  __shared__ u16 outb[MAXB];
  __shared__ u32 cnt[256], exc[256], cur[256];
  int b = blockIdx.x, t = threadIdx.x;
  int e0 = bbase[b], e1 = bbase[b+1];
  int len = e1 - e0, cap = min(len, MAXB);
  for(int i=t; i<cap; i+=256) ent[i] = packed[e0+i];
  cnt[t] = 0;
  __syncthreads();
  for(int i=t; i<len; i+=256){
    u32 v = (i < MAXB) ? ent[i] : packed[e0+i];
    atomicAdd(&cnt[(v>>16)&0xffu], 1u);
  }
  __syncthreads();
  u32 c = cnt[t];
  exc[t] = c;
  __syncthreads();
  for(int d=1; d<256; d<<=1){
    u32 v = (t>=(u32)d) ? exc[t-d] : 0u;
    __syncthreads();
    exc[t] += v;
    __syncthreads();
  }
  u32 excl = exc[t] - c;
  int node = b*NPB + t;
  if(t < NPB && node < NN) offs[node] = e0 + (int)excl;
  cur[t] = excl;
  if(b == NBUK-1 && t == 0) offs[NN] = NE;
  __syncthreads();
  for(int i=t; i<len; i+=256){
    u32 v = (i < MAXB) ? ent[i] : packed[e0+i];
    u32 p = atomicAdd(&cur[(v>>16)&0xffu], 1u);
    u16 sv = (u16)(v & 0xffffu);
    if(p < (u32)MAXB) outb[p] = sv;
    else srcs16[e0+p] = sv;
  }
  __syncthreads();
  for(int i=t; i<cap; i+=256) srcs16[e0+i] = outb[i];
}

// ---- aggregation over fp8 table (r7-proven form): one wave per node ----
// Output bf16 in TABLE (scaled) units.
template<int BPL>
__global__ __launch_bounds__(256) void k_agg8(const u8* __restrict__ hin,
                                              const int* __restrict__ offs,
                                              const u16* __restrict__ srcs,
                                              u16* __restrict__ hout){
  const int W = BPL*64;
  int node = blockIdx.x*4 + (threadIdx.x>>6);
  if(node >= NN) return;
  int lane = threadIdx.x & 63;
  const u8* hbase = hin + lane*BPL;
  float acc[BPL];
  #pragma unroll
  for(int i=0;i<BPL;i++) acc[i] = 0.f;
  int beg = offs[node], end = offs[node+1];
  for(int eb=beg; eb<end; eb+=64){
    int idx = eb + lane;
    int s = (idx < end) ? (int)srcs[idx] : 0;
    int cnt = min(64, end-eb);
    int j = 0;
    if(BPL == 8){
      for(; j+8<=cnt; j+=8){
        uint2 v[8];
        #pragma unroll
        for(int u=0;u<8;u++){
          int sj = __shfl(s, j+u, 64);
          v[u] = *(const uint2*)(hbase + (size_t)sj*W);
        }
        #pragma unroll
        for(int u=0;u<8;u++){
          f32x2 f0 = __builtin_amdgcn_cvt_pk_f32_fp8(v[u].x, false);
          f32x2 f1 = __builtin_amdgcn_cvt_pk_f32_fp8(v[u].x, true);
          f32x2 f2 = __builtin_amdgcn_cvt_pk_f32_fp8(v[u].y, false);
          f32x2 f3 = __builtin_amdgcn_cvt_pk_f32_fp8(v[u].y, true);
          acc[0]+=f0.x; acc[1]+=f0.y; acc[2]+=f1.x; acc[3]+=f1.y;
          acc[4]+=f2.x; acc[5]+=f2.y; acc[6]+=f3.x; acc[7]+=f3.y;
        }
      }
      for(; j<cnt; j++){
        int sj = __shfl(s, j, 64);
        uint2 v = *(const uint2*)(hbase + (size_t)sj*W);
        f32x2 f0 = __builtin_amdgcn_cvt_pk_f32_fp8(v.x, false);
        f32x2 f1 = __builtin_amdgcn_cvt_pk_f32_fp8(v.x, true);
        f32x2 f2 = __builtin_amdgcn_cvt_pk_f32_fp8(v.y, false);
        f32x2 f3 = __builtin_amdgcn_cvt_pk_f32_fp8(v.y, true);
        acc[0]+=f0.x; acc[1]+=f0.y; acc[2]+=f1.x; acc[3]+=f1.y;
        acc[4]+=f2.x; acc[5]+=f2.y; acc[6]+=f3.x; acc[7]+=f3.y;
      }
    } else {
      for(; j+8<=cnt; j+=8){
        u32 v[8];
        #pragma unroll
        for(int u=0;u<8;u++){
          int sj = __shfl(s, j+u, 64);
          v[u] = *(const u16*)(hbase + (size_t)sj*W);
        }
        #pragma unroll
        for(int u=0;u<8;u++){
          f32x2 f0 = __builtin_amdgcn_cvt_pk_f32_fp8(v[u], false);
          acc[0]+=f0.x; acc[1]+=f0.y;
        }
      }
      for(; j<cnt; j++){
        int sj = __shfl(s, j, 64);
        u32 v = *(const u16*)(hbase + (size_t)sj*W);
        f32x2 f0 = __builtin_amdgcn_cvt_pk_f32_fp8(v, false);
        acc[0]+=f0.x; acc[1]+=f0.y;
      }
    }
  }
  u16* o = hout + (size_t)node*W + lane*BPL;
  #pragma unroll
  for(int i=0;i<BPL;i++) o[i] = f2bf(acc[i]);
}

// ==== GEMM, r2-style: weights register-resident, stream nodes ====
// grid (ceil(NN/RPB), NEXP), 256 thr / 4 waves. Wave owns 32 cols of expert e.
// WRITE8: fp8 table out (512-stride). else: bf16 y out (512-stride, true units).
template<int TW, bool RELU, bool WRITE8>
__global__ __launch_bounds__(256) void k_gemmW(
    const u8* __restrict__ tin, const u16* __restrict__ aggb,
    const u16* __restrict__ WbfT, const float* __restrict__ bconv, int layer,
    u8* __restrict__ tout, u16* __restrict__ ybuf,
    float bias_fold, float store_fold)
{
  int wave = threadIdx.x>>6, lane = threadIdx.x&63;
  int l16 = lane&15, lq = lane>>4;
  int e = blockIdx.y;
  int cs = wave*32;
  const u16* WT = WbfT + (size_t)((e*3+layer)*HID)*256;
  const int eoff = (TW==512) ? e*128 : 0;

  // B fragments (weights), loaded ONCE, register-resident
  short8b Bf[2][8];
  #pragma unroll
  for(int ct=0; ct<2; ct++){
    const u16* wp = WT + (size_t)(cs + ct*16 + l16)*256 + lq*8;
    #pragma unroll
    for(int ks=0; ks<8; ks++)
      Bf[ct][ks] = *(const short8b*)(wp + ks*32);
  }
  const float* bias = bconv + (e*3+layer)*HID;
  f32x4 binit[2];
  #pragma unroll
  for(int ct=0; ct<2; ct++){
    f32x4 bv = *(const f32x4*)(bias + cs + ct*16 + lq*4);
    #pragma unroll
    for(int r=0;r<4;r++) binit[ct][r] = bv[r]*bias_fold;
  }

  int nbase = blockIdx.x * RPB;
  #pragma unroll 1
  for(int it=0; it<RPB/16; it++){
    int n0t = nbase + it*16;
    if(n0t >= NN) break;
    int na = n0t + l16; if(na > NN-1) na = NN-1;
    const u8*  srow = tin  + (size_t)na*TW;
    const u16* arow = aggb + (size_t)na*TW;
    short8b Af[8];
    #pragma unroll
    for(int ks=0; ks<4; ks++)
      Af[ks] = fp8x8_to_bf16(*(const uint2*)(srow + eoff + ks*32 + lq*8));
    #pragma unroll
    for(int ks=4; ks<8; ks++)
      Af[ks] = *(const short8b*)(arow + eoff + (ks-4)*32 + lq*8);
    f32x4 acc[2];
    acc[0] = binit[0]; acc[1] = binit[1];
    #pragma unroll
    for(int ks=0; ks<8; ks++){
      acc[0] = __builtin_amdgcn_mfma_f32_16x16x32_bf16(Bf[0][ks], Af[ks], acc[0], 0,0,0);
      acc[1] = __builtin_amdgcn_mfma_f32_16x16x32_bf16(Bf[1][ks], Af[ks], acc[1], 0,0,0);
    }
    int n = n0t + l16;
    if(n < NN){
      #pragma unroll
      for(int ct=0; ct<2; ct++){
        float v0,v1,v2,v3;
        if(RELU){
          v0=fmaxf(acc[ct][0],0.f)*store_fold; v1=fmaxf(acc[ct][1],0.f)*store_fold;
          v2=fmaxf(acc[ct][2],0.f)*store_fold; v3=fmaxf(acc[ct][3],0.f)*store_fold;
        } else {
          v0=acc[ct][0]*store_fold; v1=acc[ct][1]*store_fold;
          v2=acc[ct][2]*store_fold; v3=acc[ct][3]*store_fold;
        }
        if(WRITE8){
          u32 wv = __builtin_amdgcn_cvt_pk_fp8_f32(v0, v1, 0, false);
          wv = __builtin_amdgcn_cvt_pk_fp8_f32(v2, v3, wv, true);
          *(u32*)(tout + (size_t)n*512 + e*128 + cs + ct*16 + lq*4) = wv;
        } else {
          ushort4v yv;
          yv[0]=f2bf(v0); yv[1]=f2bf(v1); yv[2]=f2bf(v2); yv[3]=f2bf(v3);
          *(ushort4v*)(ybuf + (size_t)n*512 + e*128 + cs + ct*16 + lq*4) = yv;
        }
      }
    }
  }
}

// ---- final combine: out[n][j] = sum_e probs[n][e] * y[n][e][j] ----
__global__ void k_combine(const u16* __restrict__ y, const float* __restrict__ probs,
                          float* __restrict__ out){
  int t = blockIdx.x*blockDim.x + threadIdx.x;
  if(t >= NN*HID) return;
  int n = t >> 7, j = t & 127;
  const u16* yp = y + (size_t)n*(NEXP*HID);
  const float* pp = probs + n*NEXP;
  float r = pp[0]*bf2f(yp[j]) + pp[1]*bf2f(yp[HID+j])
          + pp[2]*bf2f(yp[2*HID+j]) + pp[3]*bf2f(yp[3*HID+j]);
  out[t] = r;
}

extern "C" void kernel_launch(void* const* d_in, const int* in_sizes, int n_in,
                              void* d_out, int out_size, void* d_ws, size_t ws_size,
                              hipStream_t stream){
  const float* x      = (const float*)d_in[0];
  const int*   eidx   = (const int*)d_in[1];
  const int*   batch  = (const int*)d_in[2];
  const float* Wenc   = (const float*)d_in[3];
  const float* benc   = (const float*)d_in[4];
  const float* Wself  = (const float*)d_in[5];
  const float* Wnbr   = (const float*)d_in[6];
  const float* bconv  = (const float*)d_in[7];
  const float* centers= (const float*)d_in[8];
  float* out = (float*)d_out;
  const int* src = eidx;
  const int* dst = eidx + NE;

  char* w = (char*)d_ws;
  size_t off = 0;
  auto alloc = [&](size_t b)->char*{ char* p = w + off; off = (off + b + 255) & ~(size_t)255; return p; };

  u8*  h08   = (u8*)alloc((size_t)NN*HID);            // 6.4 MB
  u8*  hA8   = (u8*)alloc((size_t)NN*NEXP*HID);       // 25.6 MB
  u8*  hB8   = (u8*)alloc((size_t)NN*NEXP*HID);       // 25.6 MB
  u16* aggb  = (u16*)alloc((size_t)NN*NEXP*HID*2);    // 51.2 MB (bf16, scaled units)
  u16* ybuf  = (u16*)alloc((size_t)NN*NEXP*HID*2);    // 51.2 MB (bf16, true units)
  u16* WbfT  = (u16*)alloc((size_t)12*HID*256*2);     // 1.57 MB
  float* probs = (float*)alloc((size_t)NN*NEXP*4);
  int* gstart = (int*)alloc(256);
  int* offs  = (int*)alloc((size_t)(NN+1)*4);
  u32* packed= (u32*)alloc((size_t)NE*4);
  u16* srcs16= (u16*)alloc((size_t)NE*2);
  int* hist  = (int*)alloc((size_t)NBLK*NBUK*4);
  int* hoff  = (int*)alloc((size_t)NBLK*NBUK*4);
  int* bbase = (int*)alloc((size_t)(NBUK+1)*4);
  if(off > ws_size) return;

  k_bounds<<<1, 32, 0, stream>>>(batch, gstart);
  k_probs<<<(NN+255)/256, 256, 0, stream>>>(batch, gstart, centers, probs);
  k_enc<<<(NN*HID+255)/256, 256, 0, stream>>>(x, Wenc, benc, h08, 0.5f);
  k_wcvtT<<<(12*HID*256+255)/256, 256, 0, stream>>>(Wself, Wnbr, WbfT);

  k_hist<<<NBLK, 256, 0, stream>>>(dst, hist);
  k_hscan<<<1, 1024, 0, stream>>>(hist, hoff, bbase);
  k_scatter<<<NBLK, 256, 0, stream>>>(src, dst, hoff, packed);
  k_build<<<NBUK, 256, 0, stream>>>(packed, bbase, offs, srcs16);

  int agrid = (NN+3)/4;                 // one wave per node
  dim3 ggrid((NN + RPB - 1)/RPB, NEXP); // (196, 4)
  // scales: esc0=0.5, escA=1/16, escB=1/32 ; agg in table (scaled) units
  k_agg8<2><<<agrid, 256, 0, stream>>>(h08, offs, srcs16, aggb);
  k_gemmW<128,true,true><<<ggrid, 256, 0, stream>>>(
      h08, aggb, WbfT, bconv, 0, hA8, nullptr, 0.5f, 0.125f);
  k_agg8<8><<<agrid, 256, 0, stream>>>(hA8, offs, srcs16, aggb);
  k_gemmW<512,true,true><<<ggrid, 256, 0, stream>>>(
      hA8, aggb, WbfT, bconv, 1, hB8, nullptr, 0.0625f, 0.5f);
  k_agg8<8><<<agrid, 256, 0, stream>>>(hB8, offs, srcs16, aggb);
  k_gemmW<512,false,false><<<ggrid, 256, 0, stream>>>(
      hB8, aggb, WbfT, bconv, 2, nullptr, ybuf, 0.03125f, 32.0f);

  k_combine<<<(NN*HID+255)/256, 256, 0, stream>>>(ybuf, probs, out);
}